// Round 5
// baseline (242.974 us; speedup 1.0000x reference)
//
#include <hip/hip_runtime.h>

constexpr int BS = 16;     // batch (vis and txt)
constexpr int S  = 4096;   // spatial
constexpr int E  = 128;    // embedding
constexpr int T  = 64;     // text tokens
constexpr int CH = 512;    // s-rows per main-kernel chunk
constexpr int NCH = S / CH;          // 8
constexpr int ETS = 520;   // ET stride (shorts), W=260 words: writes/reads 2-way (free)
constexpr int TNS = 136;   // tnL stride (shorts)
constexpr int PTS = 264;   // prepass transpose-tile stride (shorts) — round-4-proven

// ws layout:
//   shorts [0 .. 8388608)          : vn [b][s][e]  normalized bf16   (16 MB)
//   shorts [8388608 .. 16777216)   : vnT[b][e][s]  normalized bf16   (16 MB)
//   floats [8388608 .. 8388864)    : sims[b*16+i]                    (after 32 MB)
constexpr long VN_OFF  = 0;
constexpr long VNT_OFF = (long)BS * S * E;   // 8,388,608 shorts
constexpr long WS_F    = (long)BS * S * E;   // float offset == 32 MB byte offset

typedef __attribute__((ext_vector_type(8))) short bf16x8;
typedef __attribute__((ext_vector_type(4))) float f32x4;

__device__ __forceinline__ unsigned short f2bf(float x) {
    unsigned u = __float_as_uint(x);
    u += 0x7FFFu + ((u >> 16) & 1u);          // RTNE
    return (unsigned short)(u >> 16);
}
__device__ __forceinline__ float bf2f(unsigned short v) {
    return __uint_as_float(((unsigned)v) << 16);
}

// Pre-pass: normalize vis once, emit vn[s][e] and vnT[e][s] bf16.
// Grid 256 = 16 b x 16 s-tiles (256 rows each). 1024 threads.
__global__ __launch_bounds__(1024, 4)
void prep_kernel(const float* __restrict__ vis, unsigned short* __restrict__ wsv)
{
    __shared__ unsigned short Lt[128 * PTS];   // transpose tile [e][s] (67.6 KB)
    const int tid  = threadIdx.x;
    const int b    = blockIdx.x >> 4;
    const int tile = blockIdx.x & 15;
    const int s0   = tile * 256;
    const float* visb = vis + ((long)b * S + s0) * E;
    unsigned short* vn  = wsv + VN_OFF  + ((long)b * S + s0) * E;
    unsigned short* vnT = wsv + VNT_OFF + (long)b * E * S;

    // phase 1: load fp32 row-pairs, normalize, write vn + packed transpose into Lt
    {
        const int pp = tid >> 3, ee = tid & 7;   // rows 2pp,2pp+1 ; e-pairs 2ee+16k
        const float* rA = visb + (long)(pp << 1) * E + (ee << 1);
        float2 va[8], vb[8];
        float sa = 0.f, sb = 0.f;
#pragma unroll
        for (int k = 0; k < 8; ++k) {
            va[k] = *(const float2*)(rA + (k << 4));
            vb[k] = *(const float2*)(rA + E + (k << 4));
            sa = fmaf(va[k].x, va[k].x, fmaf(va[k].y, va[k].y, sa));
            sb = fmaf(vb[k].x, vb[k].x, fmaf(vb[k].y, vb[k].y, sb));
        }
        sa += __shfl_xor(sa, 1); sa += __shfl_xor(sa, 2); sa += __shfl_xor(sa, 4);
        sb += __shfl_xor(sb, 1); sb += __shfl_xor(sb, 2); sb += __shfl_xor(sb, 4);
        const float ia = 1.0f / fmaxf(sqrtf(sa), 1e-12f);
        const float ib = 1.0f / fmaxf(sqrtf(sb), 1e-12f);
        const long r0 = (long)(pp << 1) * E, r1 = r0 + E;
#pragma unroll
        for (int k = 0; k < 8; ++k) {
            const int e0 = (ee << 1) + (k << 4);
            const unsigned ax = f2bf(va[k].x * ia), ay = f2bf(va[k].y * ia);
            const unsigned bx = f2bf(vb[k].x * ib), by = f2bf(vb[k].y * ib);
            // transpose tile: pack (rowA,rowB) per e — 2-way conflict (free)
            *(unsigned*)&Lt[e0 * PTS + (pp << 1)]       = ax | (bx << 16);
            *(unsigned*)&Lt[(e0 + 1) * PTS + (pp << 1)] = ay | (by << 16);
            // vn: pack (e,e+1) per row — 32B sector-aligned global writes
            *(unsigned*)&vn[r0 + e0] = ax | (ay << 16);
            *(unsigned*)&vn[r1 + e0] = bx | (by << 16);
        }
    }
    __syncthreads();
    // phase 2: coalesced dump Lt -> vnT[e][s]
    {
        const int e = tid >> 3, sseg = (tid & 7) << 5;   // 32 s per thread
#pragma unroll
        for (int k = 0; k < 4; ++k) {
            const bf16x8 v = *(const bf16x8*)&Lt[e * PTS + sseg + (k << 3)];
            *(bf16x8*)&vnT[(long)e * S + s0 + sseg + (k << 3)] = v;
        }
    }
}

// Main: one block per (i,b). 1024 threads = 16 waves (4/SIMD). No vis staging.
__global__ __launch_bounds__(1024, 4)
void clip_main_kernel(const unsigned short* __restrict__ wsv,
                      const float* __restrict__ txt,
                      float* __restrict__ d_out,
                      float* __restrict__ wsf)
{
    __shared__ unsigned short ET[T * ETS];    // e[t][s] bf16 (66.6 KB)
    __shared__ unsigned short tnL[T * TNS];   // tn[t][e] bf16 (17.4 KB)
    __shared__ float scrA[512], scrB[512];    // cross-wave reduce

    const int tid = threadIdx.x;
    const int w   = tid >> 6;       // wave 0..15
    const int l   = tid & 63;
    const int cl  = l & 15;
    const int q   = l >> 4;
    const int b   = blockIdx.x & 15;
    const int i   = blockIdx.x >> 4;
    const bool diag = (i == b);

    // ---- stage tn (normalized bf16) into LDS ----
    {
        const int r = tid >> 4, seg = tid & 15;
        const float* tp = txt + ((long)i * T + r) * E + (seg << 3);
        const float4 a0 = *(const float4*)(tp);
        const float4 a1 = *(const float4*)(tp + 4);
        float ssq = a0.x*a0.x + a0.y*a0.y + a0.z*a0.z + a0.w*a0.w
                  + a1.x*a1.x + a1.y*a1.y + a1.z*a1.z + a1.w*a1.w;
        ssq += __shfl_xor(ssq, 1); ssq += __shfl_xor(ssq, 2);
        ssq += __shfl_xor(ssq, 4); ssq += __shfl_xor(ssq, 8);
        const float inv = 1.0f / fmaxf(sqrtf(ssq), 1e-12f);
        bf16x8 f;
        f[0]=(short)f2bf(a0.x*inv); f[1]=(short)f2bf(a0.y*inv);
        f[2]=(short)f2bf(a0.z*inv); f[3]=(short)f2bf(a0.w*inv);
        f[4]=(short)f2bf(a1.x*inv); f[5]=(short)f2bf(a1.y*inv);
        f[6]=(short)f2bf(a1.z*inv); f[7]=(short)f2bf(a1.w*inv);
        *(bf16x8*)&tnL[r * TNS + (seg << 3)] = f;
    }
    __syncthreads();

    f32x4 acc2[2];            // wc^T: e = et*16+q*4+r, t = (ntb+j)*16+cl
    acc2[0] = (f32x4){0.f,0.f,0.f,0.f};
    acc2[1] = (f32x4){0.f,0.f,0.f,0.f};
    const int et  = w >> 1;
    const int ntb = (w & 1) << 1;

    const unsigned short* vnb  = wsv + VN_OFF  + (long)b * S * E;
    const unsigned short* vntb = wsv + VNT_OFF + (long)b * E * S;
    float* attb = d_out + 1 + (long)b * (long)T * S;

    for (int ch = 0; ch < NCH; ++ch) {
        const int s0 = ch * CH;

        // ---- GEMM1: D[t][s], A = tnL, B = vn rows (global bf16, zero VALU prep) ----
        f32x4 acc1[2][4];
#pragma unroll
        for (int st = 0; st < 2; ++st)
#pragma unroll
            for (int mt = 0; mt < 4; ++mt) acc1[st][mt] = (f32x4){0.f,0.f,0.f,0.f};
        {
            const unsigned short* r0 = vnb + (long)(s0 + (w << 5) + cl) * E + (q << 3);
#pragma unroll
            for (int kk = 0; kk < 4; ++kk) {
                const bf16x8 Bf0 = *(const bf16x8*)(r0 + (kk << 5));
                const bf16x8 Bf1 = *(const bf16x8*)(r0 + 16 * E + (kk << 5));
#pragma unroll
                for (int mt = 0; mt < 4; ++mt) {
                    const bf16x8 tAk = *(const bf16x8*)&tnL[((mt << 4) + cl) * TNS + (kk << 5) + (q << 3)];
                    acc1[0][mt] = __builtin_amdgcn_mfma_f32_16x16x32_bf16(tAk, Bf0, acc1[0][mt], 0, 0, 0);
                    acc1[1][mt] = __builtin_amdgcn_mfma_f32_16x16x32_bf16(tAk, Bf1, acc1[1][mt], 0, 0, 0);
                }
            }
        }

        // ---- softmax over t per s-col; e = exp(4*s1) -> ET ----
#pragma unroll
        for (int st = 0; st < 2; ++st) {
            float ex[4][4];
            float ssum = 0.f;
#pragma unroll
            for (int mt = 0; mt < 4; ++mt)
#pragma unroll
                for (int r = 0; r < 4; ++r) {
                    const float v = __expf(acc1[st][mt][r]);   // |logit| <= ~1
                    ex[mt][r] = v; ssum += v;
                }
            ssum += __shfl_xor(ssum, 16);
            ssum += __shfl_xor(ssum, 32);
            const float csc = 4.0f / ssum;
            const int sloc = (w << 5) + (st << 4) + cl;
#pragma unroll
            for (int mt = 0; mt < 4; ++mt)
#pragma unroll
                for (int r = 0; r < 4; ++r)
                    ET[((mt << 4) + (q << 2) + r) * ETS + sloc] = f2bf(__expf(ex[mt][r] * csc));
        }
        __syncthreads();

        // ---- GEMM2: wc^T += vnT (global) x ET (LDS) ----
        {
            const unsigned short* ar = vntb + (long)((et << 4) + cl) * S + s0 + (q << 3);
            const unsigned short* b0 = &ET[((ntb << 4) + cl) * ETS + (q << 3)];
            const unsigned short* b1 = &ET[(((ntb + 1) << 4) + cl) * ETS + (q << 3)];
#pragma unroll
            for (int kk2 = 0; kk2 < 16; ++kk2) {
                const bf16x8 aV  = *(const bf16x8*)(ar + (kk2 << 5));
                const bf16x8 bE0 = *(const bf16x8*)(b0 + (kk2 << 5));
                const bf16x8 bE1 = *(const bf16x8*)(b1 + (kk2 << 5));
                acc2[0] = __builtin_amdgcn_mfma_f32_16x16x32_bf16(aV, bE0, acc2[0], 0, 0, 0);
                acc2[1] = __builtin_amdgcn_mfma_f32_16x16x32_bf16(aV, bE1, acc2[1], 0, 0, 0);
            }
        }

        // ---- diag: dump unnormalized e (att_norm computes denom + scales) ----
        if (diag) {
            const int t = tid >> 4, sb = (tid & 15) << 5;
            float* ap = attb + (long)t * S + s0 + sb;
#pragma unroll
            for (int k = 0; k < 8; ++k) {
                const ushort4 v = *(const ushort4*)&ET[t * ETS + sb + (k << 2)];
                ap[(k << 2) + 0] = bf2f(v.x);
                ap[(k << 2) + 1] = bf2f(v.y);
                ap[(k << 2) + 2] = bf2f(v.z);
                ap[(k << 2) + 3] = bf2f(v.w);
            }
        }
        __syncthreads();
    }

    // ---- cosine + LSE over t (softmax denominator cancels analytically) ----
    {
        float pn[2] = {0.f, 0.f}, pw[2] = {0.f, 0.f};
#pragma unroll
        for (int j = 0; j < 2; ++j) {
            const int t = ((ntb + j) << 4) + cl;
            const ushort4 tns = *(const ushort4*)&tnL[t * TNS + (et << 4) + (q << 2)];
            const float tv0 = bf2f(tns.x), tv1 = bf2f(tns.y), tv2 = bf2f(tns.z), tv3 = bf2f(tns.w);
            pn[j] = acc2[j][0]*tv0 + acc2[j][1]*tv1 + acc2[j][2]*tv2 + acc2[j][3]*tv3;
            pw[j] = acc2[j][0]*acc2[j][0] + acc2[j][1]*acc2[j][1]
                  + acc2[j][2]*acc2[j][2] + acc2[j][3]*acc2[j][3];
            pn[j] += __shfl_xor(pn[j], 16); pn[j] += __shfl_xor(pn[j], 32);
            pw[j] += __shfl_xor(pw[j], 16); pw[j] += __shfl_xor(pw[j], 32);
        }
        if (q == 0) {
#pragma unroll
            for (int j = 0; j < 2; ++j) {
                const int t = ((ntb + j) << 4) + cl;
                scrA[(et << 6) + t] = pn[j];
                scrB[(et << 6) + t] = pw[j];
            }
        }
        __syncthreads();
        if (tid < 64) {
            float num = 0.f, w2 = 0.f;
#pragma unroll
            for (int m = 0; m < 8; ++m) {
                num += scrA[(m << 6) + tid];
                w2  += scrB[(m << 6) + tid];
            }
            const float cosv = num / fmaxf(sqrtf(w2), 1e-20f);  // ||tn||=1; denom cancels
            float r = __expf(5.0f * cosv);
#pragma unroll
            for (int m = 1; m < 64; m <<= 1) r += __shfl_xor(r, m);
            if (tid == 0) wsf[WS_F + (b << 4) + i] = 10.0f * logf(r);
        }
    }
}

// att_maps[b][t][:]: compute denom = sum_s e, then scale in place (self-normalizing).
__global__ __launch_bounds__(256, 4)
void att_norm_kernel(float* __restrict__ d_out)
{
    __shared__ float r4[4];
    const int tid = threadIdx.x;
    const int bt = blockIdx.x;
    float* p = d_out + 1 + (long)bt * 4096;
    float v[16];
    float s = 0.f;
#pragma unroll
    for (int k = 0; k < 16; ++k) { v[k] = p[k * 256 + tid]; s += v[k]; }
#pragma unroll
    for (int m = 1; m < 64; m <<= 1) s += __shfl_xor(s, m);
    if ((tid & 63) == 0) r4[tid >> 6] = s;
    __syncthreads();
    const float inv = 1.0f / (r4[0] + r4[1] + r4[2] + r4[3]);
#pragma unroll
    for (int k = 0; k < 16; ++k) p[k * 256 + tid] = v[k] * inv;
}

// Final 16x16 symmetric cross-entropy.
__global__ __launch_bounds__(256, 1)
void loss_kernel(const float* __restrict__ wsf, float* __restrict__ d_out)
{
    __shared__ float sm[16][17];
    __shared__ float red[16];
    const int tid = threadIdx.x;
    const int bb = tid >> 4, ii = tid & 15;
    const float x = wsf[WS_F + bb * 16 + ii];
    sm[bb][ii] = x;

    float m = x;
#pragma unroll
    for (int msk = 1; msk < 16; msk <<= 1) m = fmaxf(m, __shfl_xor(m, msk));
    float s = __expf(x - m);
#pragma unroll
    for (int msk = 1; msk < 16; msk <<= 1) s += __shfl_xor(s, msk);
    const float lsm0 = x - m - logf(s);

    __syncthreads();
    const float y = sm[ii][bb];
    float m1 = y;
#pragma unroll
    for (int msk = 1; msk < 16; msk <<= 1) m1 = fmaxf(m1, __shfl_xor(m1, msk));
    float s1 = __expf(y - m1);
#pragma unroll
    for (int msk = 1; msk < 16; msk <<= 1) s1 += __shfl_xor(s1, msk);
    const float lsm1 = y - m1 - logf(s1);

    if (bb == ii) red[bb] = lsm0 + lsm1;
    __syncthreads();
    if (tid == 0) {
        float tot = 0.f;
#pragma unroll
        for (int k = 0; k < 16; ++k) tot += red[k];
        d_out[0] = -tot / 32.0f;
    }
}

extern "C" void kernel_launch(void* const* d_in, const int* in_sizes, int n_in,
                              void* d_out, int out_size, void* d_ws, size_t ws_size,
                              hipStream_t stream)
{
    const float* vis = (const float*)d_in[0];
    const float* txt = (const float*)d_in[1];
    float* out = (float*)d_out;
    unsigned short* wsv = (unsigned short*)d_ws;
    float* wsf = (float*)d_ws;

    hipLaunchKernelGGL(prep_kernel, dim3(256), dim3(1024), 0, stream, vis, wsv);
    hipLaunchKernelGGL(clip_main_kernel, dim3(BS * BS), dim3(1024), 0, stream,
                       wsv, txt, out, wsf);
    hipLaunchKernelGGL(att_norm_kernel, dim3(BS * T), dim3(256), 0, stream, out);
    hipLaunchKernelGGL(loss_kernel, dim3(1), dim3(256), 0, stream, wsf, out);
}

// Round 6
// 221.305 us; speedup vs baseline: 1.0979x; 1.0979x over previous
//
#include <hip/hip_runtime.h>

constexpr int BS = 16;     // batch (vis and txt)
constexpr int S  = 4096;   // spatial
constexpr int E  = 128;    // embedding
constexpr int T  = 64;     // text tokens
constexpr int CH = 256;    // s-rows per chunk (double-buffered)
constexpr int NCH = S / CH;          // 16
constexpr int ETS = 268;   // ET stride (shorts): W=134 words -> conflict-free writes + uniform b64 reads
constexpr int TNS = 136;   // tnL stride (shorts), 16B-aligned rows
constexpr int PTS = 264;   // prepass transpose-tile stride

// ws layout:
//   shorts [0 .. 8388608)        : vn [b][s][e]  normalized bf16   (16 MB)
//   shorts [8388608 .. 16777216) : vnT[b][e][s]  normalized bf16   (16 MB)
//   floats [8388608 .. 8388864)  : sims[b*16+i]  (after the 32 MB)
constexpr long VN_OFF  = 0;
constexpr long VNT_OFF = (long)BS * S * E;
constexpr long WS_F    = (long)BS * S * E;

typedef __attribute__((ext_vector_type(8))) short bf16x8;
typedef __attribute__((ext_vector_type(4))) short bf16x4;
typedef __attribute__((ext_vector_type(4))) float f32x4;

__device__ __forceinline__ unsigned short f2bf(float x) {
    unsigned u = __float_as_uint(x);
    u += 0x7FFFu + ((u >> 16) & 1u);          // RTNE
    return (unsigned short)(u >> 16);
}
__device__ __forceinline__ float bf2f(unsigned short v) {
    return __uint_as_float(((unsigned)v) << 16);
}
// 8B-aligned bf16x8 load from LDS (rows are 8B- but not 16B-aligned)
__device__ __forceinline__ bf16x8 ld_b64x2(const unsigned short* p) {
    const bf16x4 lo = *(const bf16x4*)p;
    const bf16x4 hi = *(const bf16x4*)(p + 4);
    bf16x8 r;
    r[0]=lo[0]; r[1]=lo[1]; r[2]=lo[2]; r[3]=lo[3];
    r[4]=hi[0]; r[5]=hi[1]; r[6]=hi[2]; r[7]=hi[3];
    return r;
}

// Pre-pass: normalize vis once, emit vn[s][e] and vnT[e][s] bf16. (round-5 proven)
__global__ __launch_bounds__(1024, 4)
void prep_kernel(const float* __restrict__ vis, unsigned short* __restrict__ wsv)
{
    __shared__ unsigned short Lt[128 * PTS];
    const int tid  = threadIdx.x;
    const int b    = blockIdx.x >> 4;
    const int tile = blockIdx.x & 15;
    const int s0   = tile * 256;
    const float* visb = vis + ((long)b * S + s0) * E;
    unsigned short* vn  = wsv + VN_OFF  + ((long)b * S + s0) * E;
    unsigned short* vnT = wsv + VNT_OFF + (long)b * E * S;

    {
        const int pp = tid >> 3, ee = tid & 7;
        const float* rA = visb + (long)(pp << 1) * E + (ee << 1);
        float2 va[8], vb[8];
        float sa = 0.f, sb = 0.f;
#pragma unroll
        for (int k = 0; k < 8; ++k) {
            va[k] = *(const float2*)(rA + (k << 4));
            vb[k] = *(const float2*)(rA + E + (k << 4));
            sa = fmaf(va[k].x, va[k].x, fmaf(va[k].y, va[k].y, sa));
            sb = fmaf(vb[k].x, vb[k].x, fmaf(vb[k].y, vb[k].y, sb));
        }
        sa += __shfl_xor(sa, 1); sa += __shfl_xor(sa, 2); sa += __shfl_xor(sa, 4);
        sb += __shfl_xor(sb, 1); sb += __shfl_xor(sb, 2); sb += __shfl_xor(sb, 4);
        const float ia = 1.0f / fmaxf(sqrtf(sa), 1e-12f);
        const float ib = 1.0f / fmaxf(sqrtf(sb), 1e-12f);
        const long r0 = (long)(pp << 1) * E, r1 = r0 + E;
#pragma unroll
        for (int k = 0; k < 8; ++k) {
            const int e0 = (ee << 1) + (k << 4);
            const unsigned ax = f2bf(va[k].x * ia), ay = f2bf(va[k].y * ia);
            const unsigned bx = f2bf(vb[k].x * ib), by = f2bf(vb[k].y * ib);
            *(unsigned*)&Lt[e0 * PTS + (pp << 1)]       = ax | (bx << 16);
            *(unsigned*)&Lt[(e0 + 1) * PTS + (pp << 1)] = ay | (by << 16);
            *(unsigned*)&vn[r0 + e0] = ax | (ay << 16);
            *(unsigned*)&vn[r1 + e0] = bx | (by << 16);
        }
    }
    __syncthreads();
    {
        const int e = tid >> 3, sseg = (tid & 7) << 5;
#pragma unroll
        for (int k = 0; k < 4; ++k) {
            const bf16x8 v = *(const bf16x8*)&Lt[e * PTS + sseg + (k << 3)];
            *(bf16x8*)&vnT[(long)e * S + s0 + sseg + (k << 3)] = v;
        }
    }
}

// Main: one block per (i,b). 1024 threads = 16 waves. Skewed pipeline:
// body k = GEMM2(k-1) [ET prev buf] + GEMM1(k)+softmax -> ET cur buf. ONE barrier/chunk.
__global__ __launch_bounds__(1024, 4)
void clip_main_kernel(const unsigned short* __restrict__ wsv,
                      const float* __restrict__ txt,
                      float* __restrict__ d_out,
                      float* __restrict__ wsf)
{
    __shared__ unsigned short ET[2][T * ETS];  // 68.6 KB
    __shared__ unsigned short tnL[T * TNS];    // 17.4 KB
    __shared__ float scrA[512], scrB[512];

    const int tid = threadIdx.x;
    const int w   = tid >> 6;       // wave 0..15
    const int l   = tid & 63;
    const int cl  = l & 15;
    const int q   = l >> 4;
    const int b   = blockIdx.x & 15;
    const int i   = blockIdx.x >> 4;
    const bool diag = (i == b);

    // ---- stage tn (normalized bf16) into LDS ----
    {
        const int r = tid >> 4, seg = tid & 15;
        const float* tp = txt + ((long)i * T + r) * E + (seg << 3);
        const float4 a0 = *(const float4*)(tp);
        const float4 a1 = *(const float4*)(tp + 4);
        float ssq = a0.x*a0.x + a0.y*a0.y + a0.z*a0.z + a0.w*a0.w
                  + a1.x*a1.x + a1.y*a1.y + a1.z*a1.z + a1.w*a1.w;
        ssq += __shfl_xor(ssq, 1); ssq += __shfl_xor(ssq, 2);
        ssq += __shfl_xor(ssq, 4); ssq += __shfl_xor(ssq, 8);
        const float inv = 1.0f / fmaxf(sqrtf(ssq), 1e-12f);
        bf16x8 f;
        f[0]=(short)f2bf(a0.x*inv); f[1]=(short)f2bf(a0.y*inv);
        f[2]=(short)f2bf(a0.z*inv); f[3]=(short)f2bf(a0.w*inv);
        f[4]=(short)f2bf(a1.x*inv); f[5]=(short)f2bf(a1.y*inv);
        f[6]=(short)f2bf(a1.z*inv); f[7]=(short)f2bf(a1.w*inv);
        *(bf16x8*)&tnL[r * TNS + (seg << 3)] = f;
    }
    __syncthreads();

    // ---- hoist tA (mt 0,1) to registers; mt 2,3 stay in LDS (VGPR budget) ----
    bf16x8 tA0[2][4];
#pragma unroll
    for (int mt = 0; mt < 2; ++mt)
#pragma unroll
        for (int kk = 0; kk < 4; ++kk)
            tA0[mt][kk] = *(const bf16x8*)&tnL[((mt << 4) + cl) * TNS + (kk << 5) + (q << 3)];

    f32x4 acc2[2];            // wc^T: e = et*16+q*4+r, t = (ntb+j)*16+cl
    acc2[0] = (f32x4){0.f,0.f,0.f,0.f};
    acc2[1] = (f32x4){0.f,0.f,0.f,0.f};
    const int et  = w >> 1;
    const int ntb = (w & 1) << 1;

    const unsigned short* vnb  = wsv + VN_OFF  + (long)b * S * E;
    const unsigned short* vntb = wsv + VNT_OFF + (long)b * E * S;
    float* attb = d_out + 1 + (long)b * (long)T * S;

    for (int ch = 0; ch <= NCH; ++ch) {
        const int cb = ch & 1, pb = cb ^ 1;

        // ---- issue GEMM1 B-loads early (consumed after GEMM2's long MFMA stretch) ----
        bf16x8 Bf[4];
        if (ch < NCH) {
            const unsigned short* r0 = vnb + (long)(ch * CH + (w << 4) + cl) * E + (q << 3);
#pragma unroll
            for (int kk = 0; kk < 4; ++kk) Bf[kk] = *(const bf16x8*)(r0 + (kk << 5));
        }

        // ---- GEMM2 for chunk ch-1: wc^T += vnT x ET[pb] ----
        if (ch > 0) {
            const int s0p = (ch - 1) * CH;
            const unsigned short* ar  = vntb + (long)((et << 4) + cl) * S + s0p + (q << 3);
            const unsigned short* e0p = &ET[pb][((ntb << 4) + cl) * ETS + (q << 3)];
            const unsigned short* e1p = e0p + (ETS << 4);
#pragma unroll
            for (int kk2 = 0; kk2 < 8; ++kk2) {
                const bf16x8 aV = *(const bf16x8*)(ar + (kk2 << 5));
                const bf16x8 b0 = ld_b64x2(e0p + (kk2 << 5));
                const bf16x8 b1 = ld_b64x2(e1p + (kk2 << 5));
                acc2[0] = __builtin_amdgcn_mfma_f32_16x16x32_bf16(aV, b0, acc2[0], 0, 0, 0);
                acc2[1] = __builtin_amdgcn_mfma_f32_16x16x32_bf16(aV, b1, acc2[1], 0, 0, 0);
            }
        }

        // ---- GEMM1(ch) + softmax -> ET[cb] ----
        if (ch < NCH) {
            f32x4 acc1[4];
#pragma unroll
            for (int mt = 0; mt < 4; ++mt) acc1[mt] = (f32x4){0.f,0.f,0.f,0.f};
#pragma unroll
            for (int kk = 0; kk < 4; ++kk) {
                acc1[0] = __builtin_amdgcn_mfma_f32_16x16x32_bf16(tA0[0][kk], Bf[kk], acc1[0], 0, 0, 0);
                acc1[1] = __builtin_amdgcn_mfma_f32_16x16x32_bf16(tA0[1][kk], Bf[kk], acc1[1], 0, 0, 0);
                const bf16x8 t2 = *(const bf16x8*)&tnL[(32 + cl) * TNS + (kk << 5) + (q << 3)];
                const bf16x8 t3 = *(const bf16x8*)&tnL[(48 + cl) * TNS + (kk << 5) + (q << 3)];
                acc1[2] = __builtin_amdgcn_mfma_f32_16x16x32_bf16(t2, Bf[kk], acc1[2], 0, 0, 0);
                acc1[3] = __builtin_amdgcn_mfma_f32_16x16x32_bf16(t3, Bf[kk], acc1[3], 0, 0, 0);
            }
            float ex[4][4];
            float ssum = 0.f;
#pragma unroll
            for (int mt = 0; mt < 4; ++mt)
#pragma unroll
                for (int r = 0; r < 4; ++r) {
                    const float v = __expf(acc1[mt][r]);   // |logit| <= ~1: no max needed
                    ex[mt][r] = v; ssum += v;
                }
            ssum += __shfl_xor(ssum, 16);
            ssum += __shfl_xor(ssum, 32);
            const float csc = 4.0f / ssum;
            const int sloc = (w << 4) + cl;
#pragma unroll
            for (int mt = 0; mt < 4; ++mt)
#pragma unroll
                for (int r = 0; r < 4; ++r)
                    ET[cb][((mt << 4) + (q << 2) + r) * ETS + sloc] = f2bf(__expf(ex[mt][r] * csc));
        }

        // ---- diag: dump chunk ch-1 (unnormalized e; att_norm scales) ----
        if (diag && ch > 0) {
            const int s0p = (ch - 1) * CH;
            const int t = tid >> 4, sg = (tid & 15) << 4;
            float* ap = attb + (long)t * S + s0p + sg;
#pragma unroll
            for (int k = 0; k < 8; ++k) {
                const ushort2 v = *(const ushort2*)&ET[pb][t * ETS + sg + (k << 1)];
                ap[(k << 1) + 0] = bf2f(v.x);
                ap[(k << 1) + 1] = bf2f(v.y);
            }
        }

        if (ch < NCH) __syncthreads();
    }

    // ---- cosine + LSE over t (softmax denominator cancels analytically) ----
    {
        float pn[2] = {0.f, 0.f}, pw[2] = {0.f, 0.f};
#pragma unroll
        for (int j = 0; j < 2; ++j) {
            const int t = ((ntb + j) << 4) + cl;
            const ushort4 tns = *(const ushort4*)&tnL[t * TNS + (et << 4) + (q << 2)];
            const float tv0 = bf2f(tns.x), tv1 = bf2f(tns.y), tv2 = bf2f(tns.z), tv3 = bf2f(tns.w);
            pn[j] = acc2[j][0]*tv0 + acc2[j][1]*tv1 + acc2[j][2]*tv2 + acc2[j][3]*tv3;
            pw[j] = acc2[j][0]*acc2[j][0] + acc2[j][1]*acc2[j][1]
                  + acc2[j][2]*acc2[j][2] + acc2[j][3]*acc2[j][3];
            pn[j] += __shfl_xor(pn[j], 16); pn[j] += __shfl_xor(pn[j], 32);
            pw[j] += __shfl_xor(pw[j], 16); pw[j] += __shfl_xor(pw[j], 32);
        }
        if (q == 0) {
#pragma unroll
            for (int j = 0; j < 2; ++j) {
                const int t = ((ntb + j) << 4) + cl;
                scrA[(et << 6) + t] = pn[j];
                scrB[(et << 6) + t] = pw[j];
            }
        }
        __syncthreads();
        if (tid < 64) {
            float num = 0.f, w2 = 0.f;
#pragma unroll
            for (int m = 0; m < 8; ++m) {
                num += scrA[(m << 6) + tid];
                w2  += scrB[(m << 6) + tid];
            }
            const float cosv = num / fmaxf(sqrtf(w2), 1e-20f);  // ||tn||=1; denom cancels
            float r = __expf(5.0f * cosv);
#pragma unroll
            for (int m = 1; m < 64; m <<= 1) r += __shfl_xor(r, m);
            if (tid == 0) wsf[WS_F + (b << 4) + i] = 10.0f * logf(r);
        }
    }
}

// Blocks 0..1023: att row (b,t) self-normalize. Block 1024: 16x16 loss.
__global__ __launch_bounds__(256, 4)
void att_norm_loss_kernel(float* __restrict__ d_out, const float* __restrict__ wsf)
{
    const int tid = threadIdx.x;
    if (blockIdx.x == BS * T) {
        __shared__ float sm[16][17];
        __shared__ float red[16];
        const int bb = tid >> 4, ii = tid & 15;
        const float x = wsf[WS_F + bb * 16 + ii];
        sm[bb][ii] = x;
        float m = x;
#pragma unroll
        for (int msk = 1; msk < 16; msk <<= 1) m = fmaxf(m, __shfl_xor(m, msk));
        float s = __expf(x - m);
#pragma unroll
        for (int msk = 1; msk < 16; msk <<= 1) s += __shfl_xor(s, msk);
        const float lsm0 = x - m - logf(s);
        __syncthreads();
        const float y = sm[ii][bb];
        float m1 = y;
#pragma unroll
        for (int msk = 1; msk < 16; msk <<= 1) m1 = fmaxf(m1, __shfl_xor(m1, msk));
        float s1 = __expf(y - m1);
#pragma unroll
        for (int msk = 1; msk < 16; msk <<= 1) s1 += __shfl_xor(s1, msk);
        const float lsm1 = y - m1 - logf(s1);
        if (bb == ii) red[bb] = lsm0 + lsm1;
        __syncthreads();
        if (tid == 0) {
            float tot = 0.f;
#pragma unroll
            for (int k = 0; k < 16; ++k) tot += red[k];
            d_out[0] = -tot / 32.0f;
        }
        return;
    }
    __shared__ float r4[4];
    const int bt = blockIdx.x;
    float* p = d_out + 1 + (long)bt * 4096;
    float v[16];
    float s = 0.f;
#pragma unroll
    for (int k = 0; k < 16; ++k) { v[k] = p[k * 256 + tid]; s += v[k]; }
#pragma unroll
    for (int m = 1; m < 64; m <<= 1) s += __shfl_xor(s, m);
    if ((tid & 63) == 0) r4[tid >> 6] = s;
    __syncthreads();
    const float inv = 1.0f / (r4[0] + r4[1] + r4[2] + r4[3]);
#pragma unroll
    for (int k = 0; k < 16; ++k) p[k * 256 + tid] = v[k] * inv;
}

extern "C" void kernel_launch(void* const* d_in, const int* in_sizes, int n_in,
                              void* d_out, int out_size, void* d_ws, size_t ws_size,
                              hipStream_t stream)
{
    const float* vis = (const float*)d_in[0];
    const float* txt = (const float*)d_in[1];
    float* out = (float*)d_out;
    unsigned short* wsv = (unsigned short*)d_ws;
    float* wsf = (float*)d_ws;

    hipLaunchKernelGGL(prep_kernel, dim3(256), dim3(1024), 0, stream, vis, wsv);
    hipLaunchKernelGGL(clip_main_kernel, dim3(BS * BS), dim3(1024), 0, stream,
                       wsv, txt, out, wsf);
    hipLaunchKernelGGL(att_norm_loss_kernel, dim3(BS * T + 1), dim3(256), 0, stream,
                       out, wsf);
}